// Round 1
// baseline (872.635 us; speedup 1.0000x reference)
//
#include <hip/hip_runtime.h>

typedef short frag  __attribute__((ext_vector_type(8)));
typedef float f32x4 __attribute__((ext_vector_type(4)));

#define E_TOT 1048576   // B*N*K
#define NK    524288    // N*K

__device__ __forceinline__ unsigned short f2bf(float f){
  unsigned int u = __float_as_uint(f);
  u += 0x7FFFu + ((u >> 16) & 1u);          // RNE
  return (unsigned short)(u >> 16);
}
__device__ __forceinline__ float frcp(float x){ return __builtin_amdgcn_rcpf(x); }
__device__ __forceinline__ float sigm(float y){
  return frcp(1.f + exp2f(-1.4426950408889634f * y));
}
__device__ __forceinline__ float gelu_f(float x){
  // tanh-approx gelu == x * sigmoid(2*sqrt(2/pi)*(x + 0.044715 x^3))
  const float C1 = 2.0f * 0.7978845608028654f * 1.4426950408889634f; // log2-scaled
  const float C2 = 0.044715f * C1;
  float z = x * fmaf(C2, x * x, C1);
  return x * frcp(1.f + exp2f(-z));
}

// ---------------- prep: pack weights to bf16 MFMA-B-fragment layout ----------------
// layer table (bf16 elem offsets in ws):
// 0 enc_in   base 0      S=8 C=8 nsrc=128
// 1-3 enc_hid base 32768/49152/65536 S=4 C=8 nsrc=128
// 4 enc_out  base 81920  S=4 C=4 nsrc=64
// 5 bias_in  base 90112  S=8 C=8 nsrc=128
// 6-8 bias_hid base 122880/139264/155648 S=4 C=8 nsrc=128
// 9 bias_out base 172032 S=4 C=1 nsrc=1 (padded to 16 cols)
// total 174080 bf16; embn (128 f32) at byte 348160
__global__ void prep_kernel(const float* __restrict__ enc_w_in,
                            const float* __restrict__ enc_w_hid,
                            const float* __restrict__ enc_w_out,
                            const float* __restrict__ bias_w_in,
                            const float* __restrict__ bias_w_hid,
                            const float* __restrict__ bias_w_out,
                            const float* __restrict__ embed_table,
                            unsigned short* __restrict__ wpk,
                            float* __restrict__ embn)
{
  int p = blockIdx.x * 256 + threadIdx.x;
  const int base[10] = {0,32768,49152,65536,81920,90112,122880,139264,155648,172032};
  const int Sv[10]   = {8,4,4,4,4,8,4,4,4,4};
  const int nsrc[10] = {128,128,128,128,64,128,128,128,128,1};
  const float* srcs[10] = {enc_w_in, enc_w_hid, enc_w_hid+16384, enc_w_hid+32768,
                           enc_w_out, bias_w_in, bias_w_hid, bias_w_hid+16384,
                           bias_w_hid+32768, bias_w_out};
  if (p < 174080) {
    int L = 0;
    for (int i = 1; i < 10; ++i) if (p >= base[i]) L = i;
    int r   = p - base[L];
    int scs = Sv[L] * 512;
    int c   = r / scs;
    int rem = r - c * scs;
    int s   = rem >> 9;
    int q   = rem & 511;
    int lane = q >> 3, elem = q & 7;
    int kl = ((lane >> 4) << 3) + elem;
    int k  = 32 * s + kl;
    int j  = (c << 4) + (lane & 15);
    float v = (j < nsrc[L]) ? srcs[L][k * nsrc[L] + j] : 0.f;
    wpk[p] = f2bf(v);
  } else if (p < 174080 + 128) {
    int q = p - 174080;          // 0..127
    int m = q >> 6;
    const float* row = embed_table + m * 64;
    float ss = 0.f;
    for (int t = 0; t < 64; ++t) { float v = row[t]; ss += v * v; }
    float nrm = fmaxf(sqrtf(ss), 1e-12f);
    embn[q] = row[q & 63] / nrm;
  }
}

// ---------------- fused main kernel ----------------
__global__ __launch_bounds__(256, 2)
void fused_kernel(const float* __restrict__ backbone,
                  const float* __restrict__ ga,
                  const int*   __restrict__ idx,
                  const float* __restrict__ enc_b_in,
                  const float* __restrict__ enc_b_hid,
                  const float* __restrict__ enc_b_out,
                  const float* __restrict__ bias_b_in,
                  const float* __restrict__ bias_b_hid,
                  const float* __restrict__ bias_b_out,
                  const unsigned short* __restrict__ wpk,
                  const float* __restrict__ embn,
                  float* __restrict__ out)
{
  __shared__ unsigned short ef[64][264];   // edge_feat bf16, stride 528B (16B aligned, bank floor)
  __shared__ float h[64][132];             // activations f32, stride 528B

  const int tid  = threadIdx.x;
  const int w    = tid >> 6;
  const int lane = tid & 63;
  const int g    = lane >> 4;      // 4-row group within MFMA tile
  const int li   = lane & 15;      // col / row-in-tile index
  const int e0   = blockIdx.x * 64;
  const int row  = 16 * w + li;    // A-frag row this lane reads
  const int orow = 16 * w + (g << 2); // D rows base this lane writes (+r)

  // ---------------- gather: build ef ----------------
  {
    const int hx = lane >> 5;            // 0=x feat, 1=y feat
    const int c4 = (lane & 31) << 2;     // float offset within 128
    for (int t = 0; t < 16; ++t) {
      int le = t * 4 + w;
      int e  = e0 + le;
      int b  = e >> 19;
      int id = idx[(1 + hx) * E_TOT + e];
      const float* src = backbone + (((b << 14) + id) << 7) + c4;
      float4 v = *(const float4*)src;
      ushort4 bv;
      bv.x = f2bf(v.x); bv.y = f2bf(v.y); bv.z = f2bf(v.z); bv.w = f2bf(v.w);
      *(ushort4*)&ef[le][c4 + (hx << 7)] = bv;
    }
  }
  __syncthreads();

  // A-frags from f32 h
  auto loadA_h = [&](frag* a){
    #pragma unroll
    for (int s = 0; s < 4; ++s) {
      const float* p = &h[row][(s << 5) + (g << 3)];
      float4 q0 = *(const float4*)p;
      float4 q1 = *(const float4*)(p + 4);
      frag t;
      t[0]=(short)f2bf(q0.x); t[1]=(short)f2bf(q0.y); t[2]=(short)f2bf(q0.z); t[3]=(short)f2bf(q0.w);
      t[4]=(short)f2bf(q1.x); t[5]=(short)f2bf(q1.y); t[6]=(short)f2bf(q1.z); t[7]=(short)f2bf(q1.w);
      a[s] = t;
    }
  };

  // layer: ef(256) -> h(128) with activation
  auto layer_from_ef = [&](int wbase, const float* bptr, bool isGelu){
    frag a[8];
    #pragma unroll
    for (int s = 0; s < 8; ++s)
      a[s] = *(const frag*)&ef[row][(s << 5) + (g << 3)];
    #pragma unroll
    for (int c = 0; c < 8; ++c) {
      f32x4 acc = {0.f, 0.f, 0.f, 0.f};
      #pragma unroll
      for (int s = 0; s < 8; ++s) {
        frag bfr = *(const frag*)(wpk + wbase + (((c << 3) + s) * 64 + lane) * 8);
        acc = __builtin_amdgcn_mfma_f32_16x16x32_bf16(a[s], bfr, acc, 0, 0, 0);
      }
      float bia = bptr[(c << 4) + li];
      #pragma unroll
      for (int r = 0; r < 4; ++r) {
        float v = acc[r] + bia;
        v = isGelu ? gelu_f(v) : fmaxf(v, 0.f);
        h[orow + r][(c << 4) + li] = v;
      }
    }
    __syncthreads();
  };

  // layer: h(128) -> h(128) with activation
  auto layer_hidden = [&](int wbase, const float* bptr, bool isGelu){
    frag a[4];
    loadA_h(a);
    #pragma unroll
    for (int c = 0; c < 8; ++c) {
      f32x4 acc = {0.f, 0.f, 0.f, 0.f};
      #pragma unroll
      for (int s = 0; s < 4; ++s) {
        frag bfr = *(const frag*)(wpk + wbase + (((c << 2) + s) * 64 + lane) * 8);
        acc = __builtin_amdgcn_mfma_f32_16x16x32_bf16(a[s], bfr, acc, 0, 0, 0);
      }
      float bia = bptr[(c << 4) + li];
      #pragma unroll
      for (int r = 0; r < 4; ++r) {
        float v = acc[r] + bia;
        v = isGelu ? gelu_f(v) : fmaxf(v, 0.f);
        h[orow + r][(c << 4) + li] = v;
      }
    }
    __syncthreads();
  };

  // ================= ENC MLP =================
  layer_from_ef(0,      enc_b_in,  false);
  layer_hidden(32768,   enc_b_hid +   0, false);
  layer_hidden(49152,   enc_b_hid + 128, false);
  layer_hidden(65536,   enc_b_hid + 256, false);

  // enc L5: h(128) -> cond(64), keep in regs
  f32x4 cond[4];
  {
    frag a[4];
    loadA_h(a);
    #pragma unroll
    for (int c = 0; c < 4; ++c) {
      f32x4 acc = {0.f, 0.f, 0.f, 0.f};
      #pragma unroll
      for (int s = 0; s < 4; ++s) {
        frag bfr = *(const frag*)(wpk + 81920 + (((c << 2) + s) * 64 + lane) * 8);
        acc = __builtin_amdgcn_mfma_f32_16x16x32_bf16(a[s], bfr, acc, 0, 0, 0);
      }
      float bia = enc_b_out[(c << 4) + li];
      #pragma unroll
      for (int r = 0; r < 4; ++r) cond[c][r] = acc[r] + bia;
    }
  }

  // normalize + sigmoid dots (per-row reduce across the 16-lane group)
  float a0v[4], a1v[4];
  {
    float em0[4], em1[4];
    #pragma unroll
    for (int c = 0; c < 4; ++c) {
      em0[c] = embn[(c << 4) + li];
      em1[c] = embn[64 + (c << 4) + li];
    }
    #pragma unroll
    for (int r = 0; r < 4; ++r) {
      float s2 = 0.f, p0 = 0.f, p1 = 0.f;
      #pragma unroll
      for (int c = 0; c < 4; ++c) {
        float v = cond[c][r];
        s2 = fmaf(v, v, s2);
        p0 = fmaf(v, em0[c], p0);
        p1 = fmaf(v, em1[c], p1);
      }
      #pragma unroll
      for (int m = 1; m <= 8; m <<= 1) {
        s2 += __shfl_xor(s2, m);
        p0 += __shfl_xor(p0, m);
        p1 += __shfl_xor(p1, m);
      }
      float inv = frcp(fmaxf(sqrtf(s2), 1e-12f));
      a0v[r] = sigm(p0 * inv);
      a1v[r] = sigm(p1 * inv);
    }
  }

  // ================= BIAS MLP =================
  layer_from_ef(90112,  bias_b_in,  true);
  layer_hidden(122880,  bias_b_hid +   0, true);
  layer_hidden(139264,  bias_b_hid + 128, true);
  layer_hidden(155648,  bias_b_hid + 256, true);

  // bias L5: h(128) -> 1 (padded to 16 cols; col0 lanes hold result)
  float biasv[4];
  {
    frag a[4];
    loadA_h(a);
    f32x4 acc = {0.f, 0.f, 0.f, 0.f};
    #pragma unroll
    for (int s = 0; s < 4; ++s) {
      frag bfr = *(const frag*)(wpk + 172032 + (s * 64 + lane) * 8);
      acc = __builtin_amdgcn_mfma_f32_16x16x32_bf16(a[s], bfr, acc, 0, 0, 0);
    }
    float bb = bias_b_out[0];
    #pragma unroll
    for (int r = 0; r < 4; ++r) biasv[r] = acc[r] + bb;
  }

  // ================= output =================
  if (li == 0) {
    #pragma unroll
    for (int r = 0; r < 4; ++r) {
      int e   = e0 + orow + r;
      int b   = e >> 19;
      int off = e & (NK - 1);
      float g0 = ga[(b << 20) + off];
      float g1 = ga[(b << 20) + NK + off];
      float bi = biasv[r];
      out[e] = a0v[r] * (g0 - bi) + a1v[r] * (g1 - bi);
    }
  }
}

extern "C" void kernel_launch(void* const* d_in, const int* in_sizes, int n_in,
                              void* d_out, int out_size, void* d_ws, size_t ws_size,
                              hipStream_t stream) {
  const float* backbone   = (const float*)d_in[0];
  const float* ga         = (const float*)d_in[1];
  const float* embed      = (const float*)d_in[2];
  const float* enc_w_in   = (const float*)d_in[3];
  const float* enc_b_in   = (const float*)d_in[4];
  const float* enc_w_hid  = (const float*)d_in[5];
  const float* enc_b_hid  = (const float*)d_in[6];
  const float* enc_w_out  = (const float*)d_in[7];
  const float* enc_b_out  = (const float*)d_in[8];
  const float* bias_w_in  = (const float*)d_in[9];
  const float* bias_b_in  = (const float*)d_in[10];
  const float* bias_w_hid = (const float*)d_in[11];
  const float* bias_b_hid = (const float*)d_in[12];
  const float* bias_w_out = (const float*)d_in[13];
  const float* bias_b_out = (const float*)d_in[14];
  const int*   indices    = (const int*)d_in[15];

  unsigned short* wpk = (unsigned short*)d_ws;
  float* embn = (float*)((char*)d_ws + 348160);

  hipLaunchKernelGGL(prep_kernel, dim3(681), dim3(256), 0, stream,
                     enc_w_in, enc_w_hid, enc_w_out,
                     bias_w_in, bias_w_hid, bias_w_out,
                     embed, wpk, embn);

  hipLaunchKernelGGL(fused_kernel, dim3(16384), dim3(256), 0, stream,
                     backbone, ga, indices,
                     enc_b_in, enc_b_hid, enc_b_out,
                     bias_b_in, bias_b_hid, bias_b_out,
                     wpk, embn, (float*)d_out);
}

// Round 2
// 628.335 us; speedup vs baseline: 1.3888x; 1.3888x over previous
//
#include <hip/hip_runtime.h>

typedef short frag  __attribute__((ext_vector_type(8)));
typedef float f32x4 __attribute__((ext_vector_type(4)));
typedef unsigned short u16;

#define E_TOT 1048576   // B*N*K
#define NK    524288    // N*K

// ws layout (bytes): wpk [0,348160); embn [348160,348672); bb16 [360448, +8388608)
#define WPK_US   174080
#define EMBN_OFF 348160
#define BB16_OFF 360448
#define WS_NEED  (BB16_OFF + 8388608)

__device__ __forceinline__ u16 f2bf(float f){
  unsigned int u = __float_as_uint(f);
  u += 0x7FFFu + ((u >> 16) & 1u);          // RNE
  return (u16)(u >> 16);
}
__device__ __forceinline__ unsigned cvtpk(float lo, float hi){
  unsigned r;
  asm("v_cvt_pk_bf16_f32 %0, %1, %2" : "=v"(r) : "v"(lo), "v"(hi));
  return r;
}
__device__ __forceinline__ float frcp(float x){ return __builtin_amdgcn_rcpf(x); }
__device__ __forceinline__ float sigm(float y){
  return frcp(1.f + exp2f(-1.4426950408889634f * y));
}
__device__ __forceinline__ float gelu_f(float x){
  const float C1 = 2.0f * 0.7978845608028654f * 1.4426950408889634f;
  const float C2 = 0.044715f * C1;
  float z = x * fmaf(C2, x * x, C1);
  return x * frcp(1.f + exp2f(-z));
}

__device__ __forceinline__ void gl_lds16(const void* g, void* l){
#if __has_builtin(__builtin_amdgcn_global_load_lds)
  __builtin_amdgcn_global_load_lds(
      (const __attribute__((address_space(1))) unsigned int*)g,
      (__attribute__((address_space(3))) unsigned int*)l, 16, 0, 0);
#else
  *(uint4*)l = *(const uint4*)g;   // fallback: reg staging (dst uniform+lane handled by caller layout)
#endif
}

template<int N> struct IC { static constexpr int value = N; };

// ---------------- prep: pack weights, A-fragment layout with phi-permutation ----------------
// A-frag element (t,s,lane,e) = W[k][j], k = 32s + 8*(lane>>4) + e + koff,
// j = 16t + 4*(((rho>>2)^(t&1))&3) + (rho&3), rho = lane&15.  (phi makes the
// inter-layer register transpose single-bpermute-per-word.)
__global__ void prep_kernel(const float* __restrict__ enc_w_in,
                            const float* __restrict__ enc_w_hid,
                            const float* __restrict__ enc_w_out,
                            const float* __restrict__ bias_w_in,
                            const float* __restrict__ bias_w_hid,
                            const float* __restrict__ bias_w_out,
                            const float* __restrict__ embed_table,
                            u16* __restrict__ wpk,
                            float* __restrict__ embn)
{
  int p = blockIdx.x * 256 + threadIdx.x;
  if (p < WPK_US) {
    const int base[12] = {0,16384,32768,49152,65536,81920,90112,106496,122880,139264,155648,172032};
    const int koff[12] = {0,128,0,0,0,0,0,128,0,0,0,0};
    const int njv[12]  = {128,128,128,128,128,64,128,128,128,128,128,1};
    const float* srcs[12] = {enc_w_in, enc_w_in, enc_w_hid, enc_w_hid+16384, enc_w_hid+32768,
                             enc_w_out, bias_w_in, bias_w_in, bias_w_hid, bias_w_hid+16384,
                             bias_w_hid+32768, bias_w_out};
    int L = 0;
    #pragma unroll
    for (int i = 1; i < 12; ++i) if (p >= base[i]) L = i;
    int r    = p - base[L];
    int f    = r >> 9;
    int lane = (r >> 3) & 63;
    int e    = r & 7;
    int s    = f & 3, t = f >> 2;
    int rho  = lane & 15, gf = lane >> 4;
    int nj   = njv[L];
    int j    = 16*t + 4*(((rho >> 2) ^ (t & 1)) & 3) + (rho & 3);
    int k    = 32*s + 8*gf + e + koff[L];
    wpk[p] = (j < nj) ? f2bf(srcs[L][k * nj + j]) : (u16)0;
  } else if (p < WPK_US + 128) {
    int q = p - WPK_US;
    int m = q >> 6;
    const float* row = embed_table + m * 64;
    float ss = 0.f;
    for (int t = 0; t < 64; ++t) { float v = row[t]; ss += v * v; }
    float nrm = fmaxf(sqrtf(ss), 1e-12f);
    embn[q] = row[q & 63] / nrm;
  }
}

// ---------------- prep: backbone f32 -> bf16 cache ----------------
__global__ void prep_backbone(const float* __restrict__ src, u16* __restrict__ dst)
{
  int i = (blockIdx.x * 256 + threadIdx.x) * 4;   // 4,194,304 total elems
  float4 v = *(const float4*)(src + i);
  unsigned lo = cvtpk(v.x, v.y), hi = cvtpk(v.z, v.w);
  *(uint2*)(dst + i) = make_uint2(lo, hi);
}

// ---------------- fused main kernel ----------------
template<bool BF>
__global__ __launch_bounds__(256, 3)
void fused_kernel(const float* __restrict__ backbone,
                  const u16*   __restrict__ bb16,
                  const float* __restrict__ ga,
                  const int*   __restrict__ idx,
                  const float* __restrict__ enc_b_in,
                  const float* __restrict__ enc_b_hid,
                  const float* __restrict__ enc_b_out,
                  const float* __restrict__ bias_b_in,
                  const float* __restrict__ bias_b_hid,
                  const float* __restrict__ bias_b_out,
                  const u16*   __restrict__ wpk,
                  const float* __restrict__ embn,
                  float* __restrict__ out)
{
  __shared__ __align__(16) u16 wbuf[16384];     // 32KB staged weights (one layer)

  const int tid  = threadIdx.x;
  const int w    = tid >> 6;
  const int lane = tid & 63;
  const int g    = lane >> 4;
  const int li   = lane & 15;
  const int eW   = blockIdx.x * 128 + w * 32;   // wave owns 32 edges (2 tiles of 16)

  // bpermute addresses (byte): src lane = li + 16*bitrev2(g), and ^16 variant
  const int A0 = 4 * (li + 16 * ((((g & 1) << 1) | (g >> 1))));
  const int A2 = A0 ^ 64;

  // ---- stage weights: linear copy, frag f occupies [f*1024,(f+1)*1024) ----
  auto stageW = [&](int base_us, int nfrag){
    for (int it = w; it < nfrag; it += 4)
      gl_lds16((const void*)(wpk + base_us + it * 512 + lane * 8),
               (void*)(&wbuf[it * 512]));
  };

  stageW(0, 32);                                 // enc L1x staged first

  // ---- per-edge gather pointers ----
  size_t rx[2], ry[2];
  #pragma unroll
  for (int et = 0; et < 2; ++et) {
    int e  = eW + 16 * et + li;
    int b  = e >> 19;
    int xid = idx[E_TOT + e];
    int yid = idx[2 * E_TOT + e];
    rx[et] = ((size_t)((b << 14) + xid)) << 7;
    ry[et] = ((size_t)((b << 14) + yid)) << 7;
  }

  f32x4 acc[8][2];
  unsigned nb[2][4][4];                          // transposed B-frags for next layer

  union FU { unsigned u[4]; frag f; };

  auto getB_g = [&](const size_t* roff, int et, int s) -> frag {
    if constexpr (BF) {
      return *(const frag*)(bb16 + roff[et] + 32 * s + 8 * g);
    } else {
      const float* p = backbone + roff[et] + 32 * s + 8 * g;
      float4 lo = *(const float4*)p, hi = *(const float4*)(p + 4);
      FU fu;
      fu.u[0] = cvtpk(lo.x, lo.y); fu.u[1] = cvtpk(lo.z, lo.w);
      fu.u[2] = cvtpk(hi.x, hi.y); fu.u[3] = cvtpk(hi.z, hi.w);
      return fu.f;
    }
  };
  auto getBx = [&](int et, int s) -> frag { return getB_g(rx, et, s); };
  auto getBy = [&](int et, int s) -> frag { return getB_g(ry, et, s); };
  auto getBn = [&](int et, int s) -> frag {
    FU fu;
    fu.u[0] = nb[et][s][0]; fu.u[1] = nb[et][s][1];
    fu.u[2] = nb[et][s][2]; fu.u[3] = nb[et][s][3];
    return fu.f;
  };

  auto zeroAcc = [&](int T_){
    #pragma unroll
    for (int t = 0; t < 8; ++t)
      if (t < T_) {
        acc[t][0] = (f32x4){0.f,0.f,0.f,0.f};
        acc[t][1] = (f32x4){0.f,0.f,0.f,0.f};
      }
  };

  auto runLayer = [&](auto TC, auto getB){
    constexpr int T_ = decltype(TC)::value;
    #pragma unroll
    for (int s = 0; s < 4; ++s) {
      frag B0 = getB(0, s);
      frag B1 = getB(1, s);
      #pragma unroll
      for (int t = 0; t < T_; ++t) {
        frag A = *(const frag*)(&wbuf[(t * 4 + s) * 512 + lane * 8]);
        acc[t][0] = __builtin_amdgcn_mfma_f32_16x16x32_bf16(A, B0, acc[t][0], 0, 0, 0);
        acc[t][1] = __builtin_amdgcn_mfma_f32_16x16x32_bf16(A, B1, acc[t][1], 0, 0, 0);
      }
    }
  };

  // bias + act + in-register transpose into nb (for 128-wide outputs, T=8)
  auto finishLayer = [&](const float* bptr, bool gelu){
    unsigned pk0[8][2], pk1[8][2];
    #pragma unroll
    for (int t = 0; t < 8; ++t) {
      float4 bv = *(const float4*)(bptr + 16 * t + 4 * (g ^ (t & 1)));
      #pragma unroll
      for (int et = 0; et < 2; ++et) {
        float x0 = acc[t][et][0] + bv.x, x1 = acc[t][et][1] + bv.y;
        float x2 = acc[t][et][2] + bv.z, x3 = acc[t][et][3] + bv.w;
        if (gelu) { x0 = gelu_f(x0); x1 = gelu_f(x1); x2 = gelu_f(x2); x3 = gelu_f(x3); }
        else      { x0 = fmaxf(x0,0.f); x1 = fmaxf(x1,0.f); x2 = fmaxf(x2,0.f); x3 = fmaxf(x3,0.f); }
        pk0[t][et] = cvtpk(x0, x1);
        pk1[t][et] = cvtpk(x2, x3);
      }
    }
    #pragma unroll
    for (int sp = 0; sp < 4; ++sp)
      #pragma unroll
      for (int et = 0; et < 2; ++et) {
        unsigned lo0 = pk0[2*sp][et], hi0 = pk0[2*sp+1][et];
        unsigned lo1 = pk1[2*sp][et], hi1 = pk1[2*sp+1][et];
        unsigned M0  = (g & 1) ? hi0 : lo0;
        unsigned M1  = (g & 1) ? hi1 : lo1;
        unsigned M0p = (g & 1) ? lo0 : hi0;
        unsigned M1p = (g & 1) ? lo1 : hi1;
        nb[et][sp][0] = (unsigned)__builtin_amdgcn_ds_bpermute(A0, (int)M0);
        nb[et][sp][1] = (unsigned)__builtin_amdgcn_ds_bpermute(A0, (int)M1);
        nb[et][sp][2] = (unsigned)__builtin_amdgcn_ds_bpermute(A2, (int)M0p);
        nb[et][sp][3] = (unsigned)__builtin_amdgcn_ds_bpermute(A2, (int)M1p);
      }
  };

  // ================= ENC MLP =================
  zeroAcc(8);
  __syncthreads();
  runLayer(IC<8>{}, getBx);                      // L1, x-features
  __syncthreads();
  stageW(16384, 32);                             // L1y
  __syncthreads();
  runLayer(IC<8>{}, getBy);                      // L1, y-features
  __syncthreads();
  stageW(32768, 32);                             // H1
  finishLayer(enc_b_in, false);
  zeroAcc(8);
  __syncthreads();
  runLayer(IC<8>{}, getBn);
  __syncthreads();
  stageW(49152, 32);                             // H2
  finishLayer(enc_b_hid + 0, false);
  zeroAcc(8);
  __syncthreads();
  runLayer(IC<8>{}, getBn);
  __syncthreads();
  stageW(65536, 32);                             // H3
  finishLayer(enc_b_hid + 128, false);
  zeroAcc(8);
  __syncthreads();
  runLayer(IC<8>{}, getBn);
  __syncthreads();
  stageW(81920, 16);                             // ENC OUT (T=4)
  finishLayer(enc_b_hid + 256, false);
  zeroAcc(4);
  __syncthreads();
  runLayer(IC<4>{}, getBn);

  // ---- epilogue: bias add, L2-normalize, sigmoid dots ----
  __syncthreads();
  stageW(90112, 32);                             // bias L1x (overlaps epilogue VALU)

  float a0v[2], a1v[2];
  {
    #pragma unroll
    for (int t = 0; t < 4; ++t) {
      float4 bv = *(const float4*)(enc_b_out + 16 * t + 4 * (g ^ (t & 1)));
      #pragma unroll
      for (int et = 0; et < 2; ++et) {
        acc[t][et][0] += bv.x; acc[t][et][1] += bv.y;
        acc[t][et][2] += bv.z; acc[t][et][3] += bv.w;
      }
    }
    float4 em0[4], em1[4];
    #pragma unroll
    for (int t = 0; t < 4; ++t) {
      em0[t] = *(const float4*)(embn + 16 * t + 4 * (g ^ (t & 1)));
      em1[t] = *(const float4*)(embn + 64 + 16 * t + 4 * (g ^ (t & 1)));
    }
    #pragma unroll
    for (int et = 0; et < 2; ++et) {
      float s2 = 0.f, p0 = 0.f, p1 = 0.f;
      #pragma unroll
      for (int t = 0; t < 4; ++t) {
        #pragma unroll
        for (int r = 0; r < 4; ++r) {
          float v = acc[t][et][r];
          float e0 = (r == 0) ? em0[t].x : (r == 1) ? em0[t].y : (r == 2) ? em0[t].z : em0[t].w;
          float e1 = (r == 0) ? em1[t].x : (r == 1) ? em1[t].y : (r == 2) ? em1[t].z : em1[t].w;
          s2 = fmaf(v, v, s2);
          p0 = fmaf(v, e0, p0);
          p1 = fmaf(v, e1, p1);
        }
      }
      s2 += __shfl_xor(s2, 16); s2 += __shfl_xor(s2, 32);
      p0 += __shfl_xor(p0, 16); p0 += __shfl_xor(p0, 32);
      p1 += __shfl_xor(p1, 16); p1 += __shfl_xor(p1, 32);
      float inv = frcp(fmaxf(sqrtf(s2), 1e-12f));
      a0v[et] = sigm(p0 * inv);
      a1v[et] = sigm(p1 * inv);
    }
  }

  // ================= BIAS MLP =================
  zeroAcc(8);
  __syncthreads();
  runLayer(IC<8>{}, getBx);
  __syncthreads();
  stageW(106496, 32);                            // bias L1y
  __syncthreads();
  runLayer(IC<8>{}, getBy);
  __syncthreads();
  stageW(122880, 32);                            // bias H1
  finishLayer(bias_b_in, true);
  zeroAcc(8);
  __syncthreads();
  runLayer(IC<8>{}, getBn);
  __syncthreads();
  stageW(139264, 32);                            // bias H2
  finishLayer(bias_b_hid + 0, true);
  zeroAcc(8);
  __syncthreads();
  runLayer(IC<8>{}, getBn);
  __syncthreads();
  stageW(155648, 32);                            // bias H3
  finishLayer(bias_b_hid + 128, true);
  zeroAcc(8);
  __syncthreads();
  runLayer(IC<8>{}, getBn);
  __syncthreads();
  stageW(172032, 4);                             // bias OUT (T=1)
  finishLayer(bias_b_hid + 256, true);
  zeroAcc(1);
  __syncthreads();
  runLayer(IC<1>{}, getBn);

  // ================= output =================
  if (g == 0) {
    float bb0 = bias_b_out[0];
    #pragma unroll
    for (int et = 0; et < 2; ++et) {
      int e   = eW + 16 * et + li;
      int b   = e >> 19;
      int off = e & (NK - 1);
      float g0 = ga[((size_t)b << 20) + off];
      float g1 = ga[((size_t)b << 20) + NK + off];
      float bi = acc[0][et][0] + bb0;             // j=0 lives at (g=0, r=0)
      out[e] = a0v[et] * (g0 - bi) + a1v[et] * (g1 - bi);
    }
  }
}

extern "C" void kernel_launch(void* const* d_in, const int* in_sizes, int n_in,
                              void* d_out, int out_size, void* d_ws, size_t ws_size,
                              hipStream_t stream) {
  const float* backbone   = (const float*)d_in[0];
  const float* ga         = (const float*)d_in[1];
  const float* embed      = (const float*)d_in[2];
  const float* enc_w_in   = (const float*)d_in[3];
  const float* enc_b_in   = (const float*)d_in[4];
  const float* enc_w_hid  = (const float*)d_in[5];
  const float* enc_b_hid  = (const float*)d_in[6];
  const float* enc_w_out  = (const float*)d_in[7];
  const float* enc_b_out  = (const float*)d_in[8];
  const float* bias_w_in  = (const float*)d_in[9];
  const float* bias_b_in  = (const float*)d_in[10];
  const float* bias_w_hid = (const float*)d_in[11];
  const float* bias_b_hid = (const float*)d_in[12];
  const float* bias_w_out = (const float*)d_in[13];
  const float* bias_b_out = (const float*)d_in[14];
  const int*   indices    = (const int*)d_in[15];

  u16*   wpk  = (u16*)d_ws;
  float* embn = (float*)((char*)d_ws + EMBN_OFF);
  u16*   bb16 = (u16*)((char*)d_ws + BB16_OFF);

  hipLaunchKernelGGL(prep_kernel, dim3(681), dim3(256), 0, stream,
                     enc_w_in, enc_w_hid, enc_w_out,
                     bias_w_in, bias_w_hid, bias_w_out,
                     embed, wpk, embn);

  bool bf = (ws_size >= (size_t)WS_NEED);
  if (bf) {
    hipLaunchKernelGGL(prep_backbone, dim3(4096), dim3(256), 0, stream, backbone, bb16);
    hipLaunchKernelGGL((fused_kernel<true>), dim3(8192), dim3(256), 0, stream,
                       backbone, bb16, ga, indices,
                       enc_b_in, enc_b_hid, enc_b_out,
                       bias_b_in, bias_b_hid, bias_b_out,
                       wpk, embn, (float*)d_out);
  } else {
    hipLaunchKernelGGL((fused_kernel<false>), dim3(8192), dim3(256), 0, stream,
                       backbone, bb16, ga, indices,
                       enc_b_in, enc_b_hid, enc_b_out,
                       bias_b_in, bias_b_hid, bias_b_out,
                       wpk, embn, (float*)d_out);
  }
}